// Round 2
// baseline (207.688 us; speedup 1.0000x reference)
//
#include <hip/hip_runtime.h>

// SparsemaxBisectLoss: x (8192 x 32000 f32), target (8192 int32) -> scalar f32
//
// tau in [max-1, max-1/d] => only elements > max-1 matter (~100 of 32000 for
// N(0,1)). Stream row once with a cur/nxt pipelined loop; per-WAVE sample
// threshold thr = wave_chunk0_max - 1 (<= row_max - 1, so candidates are a
// superset of the support); push candidates to LDS; solve tau exactly via
// Michelot iteration (the limit of the reference's 50-step bisection).

#define ROW_LEN 32000
#define ROW_V4  8000      // float4 per row
#define CAP     4096      // candidate capacity (expected ~100/row)
#define NCHUNK  8         // chunks of 1024 float4 (4096 floats)

__global__ __launch_bounds__(256) void sparsemax_row_kernel(
    const float* __restrict__ x, const int* __restrict__ target,
    float* __restrict__ row_loss, int n_rows)
{
    __shared__ float s_cand[CAP];
    __shared__ int   s_cnt;

    const int row  = blockIdx.x;
    if (row >= n_rows) return;
    const int t    = threadIdx.x;
    const int lane = t & 63;
    const int wid  = t >> 6;

    const float*  rowp = x + (size_t)row * ROW_LEN;
    const float4* rowv = (const float4*)rowp;

    float x_tgt = 0.f;
    if (t == 0) {
        s_cnt = 0;
        x_tgt = rowp[target[row]];   // single gather, latency hidden
    }

    float4 cur[4], nxt[4];
    #pragma unroll
    for (int k = 0; k < 4; ++k) cur[k] = rowv[t + k * 256];  // chunk 0, all in-range

    // per-wave threshold: wave's 1024-element sample max - 1  (<= row_max - 1)
    float lm = -1e30f;
    #pragma unroll
    for (int k = 0; k < 4; ++k)
        lm = fmaxf(lm, fmaxf(fmaxf(cur[k].x, cur[k].y), fmaxf(cur[k].z, cur[k].w)));
    #pragma unroll
    for (int o = 32; o >= 1; o >>= 1)
        lm = fmaxf(lm, __shfl_xor(lm, o));
    const float thr = lm - 1.0f;

    __syncthreads();   // s_cnt = 0 visible before any push

    for (int c = 0; c < NCHUNK; ++c) {
        // issue next chunk's loads BEFORE consuming current chunk
        if (c + 1 < NCHUNK) {
            const int base = (c + 1) * 1024 + t;
            #pragma unroll
            for (int k = 0; k < 4; ++k) {
                const int idx = base + k * 256;
                nxt[k] = (idx < ROW_V4) ? rowv[idx]
                                        : make_float4(-1e30f, -1e30f, -1e30f, -1e30f);
            }
        }
        // filter current chunk; per-float4 early-out (common case: 3 vmax + 1 branch)
        #pragma unroll
        for (int k = 0; k < 4; ++k) {
            const float4 v = cur[k];
            const float m4 = fmaxf(fmaxf(v.x, v.y), fmaxf(v.z, v.w));
            if (m4 > thr) {
                const float vals[4] = {v.x, v.y, v.z, v.w};
                #pragma unroll
                for (int e = 0; e < 4; ++e) {
                    if (vals[e] > thr) {
                        const int idx = atomicAdd(&s_cnt, 1);
                        if (idx < CAP) s_cand[idx] = vals[e];
                    }
                }
            }
        }
        #pragma unroll
        for (int k = 0; k < 4; ++k) cur[k] = nxt[k];
    }
    __syncthreads();

    // Epilogue on wave 0: exact tau via Michelot active-set iteration, then loss.
    if (wid == 0) {
        int m = s_cnt;
        if (m > CAP) m = CAP;

        float tau = -1e30f;   // first pass includes all candidates
        int c_prev = -1;
        for (int it = 0; it < 100; ++it) {
            float s = 0.f; int cnt = 0;
            for (int j = lane; j < m; j += 64) {
                const float v = s_cand[j];
                if (v > tau) { s += v; cnt++; }
            }
            #pragma unroll
            for (int o = 32; o >= 1; o >>= 1) {
                s   += __shfl_xor(s, o);
                cnt += __shfl_xor(cnt, o);
            }
            const float tau_new = (s - 1.0f) / (float)cnt;
            if (cnt == c_prev) { tau = tau_new; break; }  // active set stable -> exact
            c_prev = cnt;
            tau = tau_new;
        }

        float sp = 0.f, sp2 = 0.f, spx = 0.f;
        for (int j = lane; j < m; j += 64) {
            const float v = s_cand[j];
            const float p = v - tau;
            if (p > 0.f) { sp += p; sp2 += p * p; spx += p * v; }
        }
        #pragma unroll
        for (int o = 32; o >= 1; o >>= 1) {
            sp  += __shfl_xor(sp, o);
            sp2 += __shfl_xor(sp2, o);
            spx += __shfl_xor(spx, o);
        }
        if (lane == 0) {
            const float inv  = 1.0f / sp;                 // ensure_sum_one
            const float loss = 0.5f * (1.0f - sp2 * inv * inv)
                             + spx * inv - x_tgt;
            row_loss[row] = loss;
        }
    }
}

// Deterministic mean reduction of n row losses -> out[0]
__global__ __launch_bounds__(256) void mean_kernel(
    const float* __restrict__ row_loss, float* __restrict__ out, int n)
{
    __shared__ float s_red[4];
    const int t = threadIdx.x;
    const int lane = t & 63, wid = t >> 6;
    float s = 0.f;
    for (int i = t; i < n; i += 256) s += row_loss[i];
    #pragma unroll
    for (int o = 32; o >= 1; o >>= 1) s += __shfl_xor(s, o);
    if (lane == 0) s_red[wid] = s;
    __syncthreads();
    if (t == 0)
        out[0] = (s_red[0] + s_red[1] + s_red[2] + s_red[3]) / (float)n;
}

extern "C" void kernel_launch(void* const* d_in, const int* in_sizes, int n_in,
                              void* d_out, int out_size, void* d_ws, size_t ws_size,
                              hipStream_t stream)
{
    const float* x      = (const float*)d_in[0];
    const int*   target = (const int*)d_in[1];
    float*       out    = (float*)d_out;
    const int n_rows = in_sizes[1];          // 8192
    float* row_loss = (float*)d_ws;

    sparsemax_row_kernel<<<n_rows, 256, 0, stream>>>(x, target, row_loss, n_rows);
    mean_kernel<<<1, 256, 0, stream>>>(row_loss, out, n_rows);
}

// Round 3
// 177.357 us; speedup vs baseline: 1.1710x; 1.1710x over previous
//
#include <hip/hip_runtime.h>

// SparsemaxBisectLoss: x (8192 x 32000 f32), target (8192 int32) -> scalar f32
//
// tau in [max-1, max-1/d] => only elements > max-1 matter (~100 of 32000 for
// N(0,1)). Stream each row ONCE (memory-bound: 1.048 GB mandatory read):
// per-wave sample threshold thr = wave_chunk0_max - 1 (<= row_max - 1, so the
// candidate set is a superset of the support); push candidates to LDS; solve
// tau exactly with Michelot active-set iteration (the limit of the reference's
// 50-step bisection; agrees to ~1 ulp, threshold is 8.6e-2).
//
// Round-3 changes: nontemporal loads (read-once stream, evict-first), 8-deep
// load batches per thread (more MLP), no manual cur/nxt pipeline (regressed).

#define ROW_LEN 32000
#define ROW_V4  8000      // float4 per row
#define CAP     4096      // candidate capacity (expected ~100/row)

typedef float v4f __attribute__((ext_vector_type(4)));

__device__ __forceinline__ float max4(v4f v) {
    return fmaxf(fmaxf(v[0], v[1]), fmaxf(v[2], v[3]));
}

__global__ __launch_bounds__(256) void sparsemax_row_kernel(
    const float* __restrict__ x, const int* __restrict__ target,
    float* __restrict__ row_loss, int n_rows)
{
    __shared__ float s_cand[CAP];
    __shared__ int   s_cnt;

    const int row  = blockIdx.x;
    if (row >= n_rows) return;
    const int t    = threadIdx.x;
    const int lane = t & 63;
    const int wid  = t >> 6;

    const float* rowp = x + (size_t)row * ROW_LEN;
    const v4f*   rowv = (const v4f*)rowp;

    float x_tgt = 0.f;
    if (t == 0) {
        s_cnt = 0;
        x_tgt = rowp[target[row]];   // single gather, latency hidden
    }

    // ---- chunk 0: 8 x float4 per thread (2048 v4 = 8192 floats, all in-range)
    v4f v[8];
    #pragma unroll
    for (int k = 0; k < 8; ++k)
        v[k] = __builtin_nontemporal_load(rowv + t + k * 256);

    // per-wave threshold from this wave's 2048-element sample (<= row_max - 1)
    float lm = -1e30f;
    #pragma unroll
    for (int k = 0; k < 8; ++k) lm = fmaxf(lm, max4(v[k]));
    #pragma unroll
    for (int o = 32; o >= 1; o >>= 1) lm = fmaxf(lm, __shfl_xor(lm, o));
    const float thr = lm - 1.0f;

    __syncthreads();   // s_cnt = 0 visible before any push

    // ---- filter chunk 0, then stream+filter chunks 1..3
    for (int c = 0; ; ++c) {
        #pragma unroll
        for (int k = 0; k < 8; ++k) {
            if (max4(v[k]) > thr) {
                #pragma unroll
                for (int e = 0; e < 4; ++e) {
                    const float val = v[k][e];
                    if (val > thr) {
                        const int idx = atomicAdd(&s_cnt, 1);
                        if (idx < CAP) s_cand[idx] = val;
                    }
                }
            }
        }
        if (c == 3) break;
        const int base = (c + 1) * 2048 + t;
        #pragma unroll
        for (int k = 0; k < 8; ++k) {
            const int idx = base + k * 256;
            if (idx < ROW_V4) v[k] = __builtin_nontemporal_load(rowv + idx);
            else              v[k] = (v4f){-1e30f, -1e30f, -1e30f, -1e30f};
        }
    }
    __syncthreads();

    // ---- epilogue on wave 0: exact tau via Michelot, then loss
    if (wid == 0) {
        int m = s_cnt;
        if (m > CAP) m = CAP;

        float tau = -1e30f;   // first pass includes all candidates
        int c_prev = -1;
        for (int it = 0; it < 100; ++it) {
            float s = 0.f; int cnt = 0;
            for (int j = lane; j < m; j += 64) {
                const float cv = s_cand[j];
                if (cv > tau) { s += cv; cnt++; }
            }
            #pragma unroll
            for (int o = 32; o >= 1; o >>= 1) {
                s   += __shfl_xor(s, o);
                cnt += __shfl_xor(cnt, o);
            }
            const float tau_new = (s - 1.0f) / (float)cnt;
            if (cnt == c_prev) { tau = tau_new; break; }  // active set stable
            c_prev = cnt;
            tau = tau_new;
        }

        float sp = 0.f, sp2 = 0.f, spx = 0.f;
        for (int j = lane; j < m; j += 64) {
            const float cv = s_cand[j];
            const float p = cv - tau;
            if (p > 0.f) { sp += p; sp2 += p * p; spx += p * cv; }
        }
        #pragma unroll
        for (int o = 32; o >= 1; o >>= 1) {
            sp  += __shfl_xor(sp, o);
            sp2 += __shfl_xor(sp2, o);
            spx += __shfl_xor(spx, o);
        }
        if (lane == 0) {
            const float inv  = 1.0f / sp;                 // ensure_sum_one
            const float loss = 0.5f * (1.0f - sp2 * inv * inv)
                             + spx * inv - x_tgt;
            row_loss[row] = loss;
        }
    }
}

// Deterministic mean reduction of n row losses -> out[0]
__global__ __launch_bounds__(256) void mean_kernel(
    const float* __restrict__ row_loss, float* __restrict__ out, int n)
{
    __shared__ float s_red[4];
    const int t = threadIdx.x;
    const int lane = t & 63, wid = t >> 6;
    float s = 0.f;
    for (int i = t; i < n; i += 256) s += row_loss[i];
    #pragma unroll
    for (int o = 32; o >= 1; o >>= 1) s += __shfl_xor(s, o);
    if (lane == 0) s_red[wid] = s;
    __syncthreads();
    if (t == 0)
        out[0] = (s_red[0] + s_red[1] + s_red[2] + s_red[3]) / (float)n;
}

extern "C" void kernel_launch(void* const* d_in, const int* in_sizes, int n_in,
                              void* d_out, int out_size, void* d_ws, size_t ws_size,
                              hipStream_t stream)
{
    const float* x      = (const float*)d_in[0];
    const int*   target = (const int*)d_in[1];
    float*       out    = (float*)d_out;
    const int n_rows = in_sizes[1];          // 8192
    float* row_loss = (float*)d_ws;

    sparsemax_row_kernel<<<n_rows, 256, 0, stream>>>(x, target, row_loss, n_rows);
    mean_kernel<<<1, 256, 0, stream>>>(row_loss, out, n_rows);
}